// Round 15
// baseline (135.447 us; speedup 1.0000x reference)
//
#include <hip/hip_runtime.h>
#include <hip/hip_bf16.h>

// SpikingPolicyNet: B=8192, D_in=256, H=1024, D_out=64, T=15, TAU=20, V_TH=1
//
// Pipeline:
//  K0 : W2 -> W2cb (bf16 W2^T, row 1024 zeroed = sentinel); zero flags[8192].
//  K1 : bf16-MFMA x@W1.T; epilogue folds b1, emits closed-form spike interval
//       k = ceil(log2(1-1/I)/log2(0.95)) as byte plane kb[b][j] (spikes at
//       t = k,2k,...; I1 time-invariant).
//  K2 : WAVE-PER-QUARTER-ROW, ZERO BARRIERS. Each wave owns 256 columns,
//       reads the full kb row, ballot-compacts spikers into 3 class lists
//       {k<=7},{8..11},{12..15} in wave-private LDS (no atomics), then an
//       8-deep explicit-scalar gather (R8-proven shape) into 3 static relu
//       sums Rs,R1,R2. Certificate M = b2 + Rs + max(R1,R2) >= max_t I2_t
//       (t<=7: I2 <= b2+Rs; t>=8: only divisor >=8 of t is t, and signed
//       subset-sum <= relu-sum of its class). M <= 0.995 (margin covers
//       bf16-sum slack ~2e-3 + fp drift) + induction v2_t <= M(1-.95^t)
//       proves zero s2 spikes -> out = bout bit-exact (absmax==0 R1-R14
//       incl fp32 R1; R14 validated this bound's ~zero flag rate).
//       Cert fail / capacity overflow -> flags[row] = 1.
//  K3 : exact per-step divmask resim for flagged rows only (grid-stride,
//       batched flag reads; ~1 us when no flags). Overwrites out[row].

#define B_SZ   8192
#define D_IN   256
#define H_SZ   1024
#define D_OUT  64
#define T_STEPS 15
#define SKIP_THR 0.995f

typedef __attribute__((ext_vector_type(8))) short short8;
typedef __attribute__((ext_vector_type(4))) float f32x4;

static __device__ __forceinline__ unsigned int pk_bf16(float lo, float hi) {
    return (__builtin_bit_cast(unsigned int, hi) & 0xffff0000u) |
           (__builtin_bit_cast(unsigned int, lo) >> 16);
}
static __device__ __forceinline__ f32x4 unp4(uint2 w) {
    f32x4 r;
    r.x = __builtin_bit_cast(float, w.x << 16);
    r.y = __builtin_bit_cast(float, w.x & 0xffff0000u);
    r.z = __builtin_bit_cast(float, w.y << 16);
    r.w = __builtin_bit_cast(float, w.y & 0xffff0000u);
    return r;
}
static __device__ __forceinline__ f32x4 relu4(f32x4 a) {
    a.x = fmaxf(a.x, 0.f); a.y = fmaxf(a.y, 0.f);
    a.z = fmaxf(a.z, 0.f); a.w = fmaxf(a.w, 0.f);
    return a;
}
static __device__ __forceinline__ f32x4 vmax4(f32x4 a, f32x4 b) {
    f32x4 r;
    r.x = fmaxf(a.x, b.x); r.y = fmaxf(a.y, b.y);
    r.z = fmaxf(a.z, b.z); r.w = fmaxf(a.w, b.w);
    return r;
}
__host__ __device__ constexpr unsigned divmask(int t) {   // bit k set iff k | t
    unsigned m = 0;
    for (int k = 1; k <= 15; ++k) if (t % k == 0) m |= 1u << k;
    return m;
}

// ---------------------------------------------------------------- K0: W2 -> W2cb (+pad) + flags reset
__global__ __launch_bounds__(256) void k0_transpose(const float* __restrict__ W2,
                                                    unsigned short* __restrict__ W2cb,
                                                    int* __restrict__ flags) {
    __shared__ float tile[32][33];
    const int bx = blockIdx.x * 32;
    const int by = blockIdx.y * 32;
    const int tx = threadIdx.x;
    const int ty = threadIdx.y;
    #pragma unroll
    for (int i = ty; i < 32; i += 8)
        tile[i][tx] = W2[(by + i) * H_SZ + bx + tx];
    __syncthreads();
    #pragma unroll
    for (int i = ty; i < 32; i += 8)
        W2cb[(size_t)(bx + i) * H_SZ + by + tx] =
            (unsigned short)(__builtin_bit_cast(unsigned int, tile[tx][i]) >> 16);
    if (blockIdx.x == 0 && blockIdx.y == 0) {                   // zero sentinel row 1024
        const int t = ty * 32 + tx;
        #pragma unroll
        for (int i = 0; i < 4; ++i)
            W2cb[(size_t)H_SZ * H_SZ + i * 256 + t] = 0;
    }
    const int lb = blockIdx.y * 32 + blockIdx.x;                 // zero flags[8192]
    if (lb < 32) flags[lb * 256 + ty * 32 + tx] = 0;
}

// ---------------------------------------------------------------- K1: interval byte-plane from x@W1.T+b1
__global__ __launch_bounds__(256) void k1_mfma(const float* __restrict__ A,
                                               const float* __restrict__ Bw,
                                               const float* __restrict__ b1,
                                               unsigned char* __restrict__ kb) {
    __shared__ unsigned int As4[2048];   // 128 rows x 32 bf16, 16B-chunk XOR swizzle
    __shared__ unsigned int Bs4[2048];
    const int tid  = threadIdx.x;
    const int m0   = blockIdx.x * 128;
    const int n0   = blockIdx.y * 128;
    const int lane = tid & 63;
    const int wid  = tid >> 6;
    const int wr   = wid >> 1, wc = wid & 1;

    const int row0 = tid >> 2;
    const int row1 = row0 + 64;
    const int q0   = tid & 3;

    f32x4 acc[4][4] = {};
    float4 s0[8], s1[8];

    auto LOAD = [&](float4* s, int kbk) {
        const float* pa0 = A  + (m0 + row0) * D_IN + kbk + q0 * 8;
        const float* pa1 = A  + (m0 + row1) * D_IN + kbk + q0 * 8;
        const float* pb0 = Bw + (n0 + row0) * D_IN + kbk + q0 * 8;
        const float* pb1 = Bw + (n0 + row1) * D_IN + kbk + q0 * 8;
        s[0] = *(const float4*)pa0; s[1] = *(const float4*)(pa0 + 4);
        s[2] = *(const float4*)pa1; s[3] = *(const float4*)(pa1 + 4);
        s[4] = *(const float4*)pb0; s[5] = *(const float4*)(pb0 + 4);
        s[6] = *(const float4*)pb1; s[7] = *(const float4*)(pb1 + 4);
    };
    auto WRITE = [&](const float4* s) {
        const int i0 = row0 * 16 + (q0 ^ ((row0 >> 1) & 3)) * 4;
        const int i1 = row1 * 16 + (q0 ^ ((row1 >> 1) & 3)) * 4;
        *(uint4*)&As4[i0] = make_uint4(pk_bf16(s[0].x, s[0].y), pk_bf16(s[0].z, s[0].w),
                                       pk_bf16(s[1].x, s[1].y), pk_bf16(s[1].z, s[1].w));
        *(uint4*)&As4[i1] = make_uint4(pk_bf16(s[2].x, s[2].y), pk_bf16(s[2].z, s[2].w),
                                       pk_bf16(s[3].x, s[3].y), pk_bf16(s[3].z, s[3].w));
        *(uint4*)&Bs4[i0] = make_uint4(pk_bf16(s[4].x, s[4].y), pk_bf16(s[4].z, s[4].w),
                                       pk_bf16(s[5].x, s[5].y), pk_bf16(s[5].z, s[5].w));
        *(uint4*)&Bs4[i1] = make_uint4(pk_bf16(s[6].x, s[6].y), pk_bf16(s[6].z, s[6].w),
                                       pk_bf16(s[7].x, s[7].y), pk_bf16(s[7].z, s[7].w));
    };
    auto COMPUTE = [&]() {
        short8 afr[4], bfr[4];
        const int q  = lane >> 4;
        const int lr = lane & 15;
        #pragma unroll
        for (int mf = 0; mf < 4; ++mf) {
            const int ra = wr * 64 + mf * 16 + lr;
            afr[mf] = *(const short8*)&As4[ra * 16 + (q ^ ((ra >> 1) & 3)) * 4];
            const int rb = wc * 64 + mf * 16 + lr;
            bfr[mf] = *(const short8*)&Bs4[rb * 16 + (q ^ ((rb >> 1) & 3)) * 4];
        }
        #pragma unroll
        for (int mf = 0; mf < 4; ++mf)
            #pragma unroll
            for (int nf = 0; nf < 4; ++nf)
                acc[mf][nf] = __builtin_amdgcn_mfma_f32_16x16x32_bf16(
                    afr[mf], bfr[nf], acc[mf][nf], 0, 0, 0);
    };

    LOAD(s0, 0);
    for (int kk = 0; kk < D_IN; kk += 64) {
        if (kk + 32 < D_IN) LOAD(s1, kk + 32);
        __syncthreads();
        WRITE(s0);
        __syncthreads();
        COMPUTE();
        if (kk + 64 < D_IN) LOAD(s0, kk + 64);
        __syncthreads();
        WRITE(s1);
        __syncthreads();
        COMPUTE();
    }

    // Epilogue: I = acc + b1[col]; k = ceil(log2(1-1/I)*-13.5134035), 0 = none.
    const int lr = lane & 15;
    const int qq = lane >> 4;
    float b1v[4];
    #pragma unroll
    for (int nf = 0; nf < 4; ++nf) b1v[nf] = b1[n0 + wc * 64 + nf * 16 + lr];

    #pragma unroll
    for (int mf = 0; mf < 4; ++mf) {
        const int rbase = m0 + wr * 64 + mf * 16 + qq * 4;
        #pragma unroll
        for (int nf = 0; nf < 4; ++nf) {
            const int c = n0 + wc * 64 + nf * 16 + lr;
            #pragma unroll
            for (int r = 0; r < 4; ++r) {
                const float I = acc[mf][nf][r] + b1v[nf];
                int k = 0;
                if (I > 1.8632055f) {
                    const float l2 = __builtin_amdgcn_logf(1.0f - __builtin_amdgcn_rcpf(I));
                    int kc = (int)__builtin_ceilf(l2 * -13.5134035f);
                    k = kc < 1 ? 1 : (kc > 15 ? 15 : kc);
                }
                kb[(size_t)(rbase + r) * H_SZ + c] = (unsigned char)k;
            }
        }
    }
}

// ---------------------------------------------------------------- K2: wave-per-quarter-row certificate
#define GATHER(BS, CNT, TGT)                                                  \
    for (int s = 0; s < (CNT); s += 8) {                                      \
        const uint4 e = *(const uint4*)&Wl[(BS) + s];                         \
        const unsigned ex = (unsigned)__builtin_amdgcn_readfirstlane((int)e.x);   \
        const unsigned ey = (unsigned)__builtin_amdgcn_readfirstlane((int)e.y);   \
        const unsigned ez = (unsigned)__builtin_amdgcn_readfirstlane((int)e.z);   \
        const unsigned eu = (unsigned)__builtin_amdgcn_readfirstlane((int)e.w);   \
        const uint2 w0 = *(const uint2*)(W2cb + ((size_t)(ex & 0xffffu) << 10) + jc); \
        const uint2 w1 = *(const uint2*)(W2cb + ((size_t)(ex >> 16) << 10) + jc);     \
        const uint2 w2 = *(const uint2*)(W2cb + ((size_t)(ey & 0xffffu) << 10) + jc); \
        const uint2 w3 = *(const uint2*)(W2cb + ((size_t)(ey >> 16) << 10) + jc);     \
        const uint2 w4 = *(const uint2*)(W2cb + ((size_t)(ez & 0xffffu) << 10) + jc); \
        const uint2 w5 = *(const uint2*)(W2cb + ((size_t)(ez >> 16) << 10) + jc);     \
        const uint2 w6 = *(const uint2*)(W2cb + ((size_t)(eu & 0xffffu) << 10) + jc); \
        const uint2 w7 = *(const uint2*)(W2cb + ((size_t)(eu >> 16) << 10) + jc);     \
        TGT += relu4(unp4(w0)); TGT += relu4(unp4(w1));                       \
        TGT += relu4(unp4(w2)); TGT += relu4(unp4(w3));                       \
        TGT += relu4(unp4(w4)); TGT += relu4(unp4(w5));                       \
        TGT += relu4(unp4(w6)); TGT += relu4(unp4(w7));                       \
    }

__global__ __launch_bounds__(256) void k2_cert(const unsigned char* __restrict__ kb,
                                               const unsigned short* __restrict__ W2cb,
                                               const float* __restrict__ b2,
                                               const float* __restrict__ bout,
                                               int* __restrict__ flags,
                                               float* __restrict__ out) {
    const int b    = blockIdx.x;
    const int tid  = threadIdx.x;
    const int wid  = tid >> 6;
    const int lane = tid & 63;
    const int jc   = wid * 256 + lane * 4;      // this wave's column slice

    __shared__ __align__(16) unsigned short ew[4][1056];   // 3 class segs x 352 / wave
    unsigned short* Wl = ew[wid];

    const uint4 kw = *(const uint4*)(kb + (size_t)b * H_SZ + lane * 16);
    const f32x4 b2q = *(const f32x4*)&b2[jc];
    const unsigned long long lt = (1ull << lane) - 1ull;

    // ---- ballot-compacted class lists (wave-private, no atomics, no barriers)
    int c0 = 0, c1 = 0, c2 = 0;                 // wave-uniform class counts
    const unsigned kws[4] = {kw.x, kw.y, kw.z, kw.w};
    #pragma unroll
    for (int u = 0; u < 16; ++u) {
        const int k = (int)((kws[u >> 2] >> ((u & 3) * 8)) & 0xffu);
        const bool s1 = (k >= 1) && (k <= 7);
        const bool s2 = (k >= 8) && (k <= 11);
        const bool s3 = (k >= 12);
        const unsigned long long m1 = __ballot(s1);
        const unsigned long long m2 = __ballot(s2);
        const unsigned long long m3 = __ballot(s3);
        const unsigned short j = (unsigned short)(lane * 16 + u);
        if (s1) Wl[c0 + (int)__popcll(m1 & lt)] = j;
        if (s2) Wl[352 + c1 + (int)__popcll(m2 & lt)] = j;
        if (s3) Wl[704 + c2 + (int)__popcll(m3 & lt)] = j;
        c0 += (int)__popcll(m1);
        c1 += (int)__popcll(m2);
        c2 += (int)__popcll(m3);
    }

    if (c0 > 344 || c1 > 344 || c2 > 344) {     // capacity overflow (P ~ 0): exact path
        if (lane == 0) flags[b] = 1;
    } else {
        if (lane < 8) {                          // sentinel-pad each class tail to x8
            Wl[c0 + lane]       = (unsigned short)H_SZ;
            Wl[352 + c1 + lane] = (unsigned short)H_SZ;
            Wl[704 + c2 + lane] = (unsigned short)H_SZ;
        }
        f32x4 Rs = {0,0,0,0}, R1 = {0,0,0,0}, R2 = {0,0,0,0};
        GATHER(0,   c0, Rs)
        GATHER(352, c1, R1)
        GATHER(704, c2, R2)

        const f32x4 rm = vmax4(R1, R2);
        const float M0 = b2q.x + Rs.x + rm.x;
        const float M1 = b2q.y + Rs.y + rm.y;
        const float M2 = b2q.z + Rs.z + rm.z;
        const float M3 = b2q.w + Rs.w + rm.w;
        if ((M0 > SKIP_THR) || (M1 > SKIP_THR) || (M2 > SKIP_THR) || (M3 > SKIP_THR))
            flags[b] = 1;                        // racy same-value store: benign
    }

    if (wid == 0) out[(size_t)b * D_OUT + lane] = bout[lane];   // k3 overwrites if flagged
}

// ---------------------------------------------------------------- K3: exact resim for flagged rows
#define STEP                                                                  \
    { v2 = v2 * 0.95f + i2 * 0.05f;                                           \
      if (v2.x > 1.0f) { v2.x = 0.f; ++c0; }                                  \
      if (v2.y > 1.0f) { v2.y = 0.f; ++c1; }                                  \
      if (v2.z > 1.0f) { v2.z = 0.f; ++c2; }                                  \
      if (v2.w > 1.0f) { v2.w = 0.f; ++c3; } }

#define TPASS(T)                                                              \
    { constexpr unsigned dm = divmask(T);                                     \
      for (int i = 0; i < e3; i += 2) {                                       \
          const unsigned ee = (unsigned)__builtin_amdgcn_readfirstlane(       \
              (int)*(const unsigned int*)&ent[i]);                            \
          const int j1 = (int)(ee & 0xfffu), k1 = (int)((ee >> 12) & 15u);    \
          const int j2 = (int)((ee >> 16) & 0xfffu), k2 = (int)(ee >> 28);    \
          if ((dm >> k1) & 1) {                                               \
              const uint2 w = *(const uint2*)(W2cb + ((size_t)j1 << 10) + jcc);\
              i2 += unp4(w); }                                                \
          if ((dm >> k2) & 1) {                                               \
              const uint2 w = *(const uint2*)(W2cb + ((size_t)j2 << 10) + jcc);\
              i2 += unp4(w); }                                                \
      } }

__global__ __launch_bounds__(256) void k3_rare(const unsigned char* __restrict__ kb,
                                               const unsigned short* __restrict__ W2cb,
                                               const float* __restrict__ b2,
                                               const float* __restrict__ Wout,
                                               const float* __restrict__ bout,
                                               const int* __restrict__ flags,
                                               float* __restrict__ out) {
    __shared__ int f[32];
    __shared__ int cnt, tot;
    __shared__ __align__(8) unsigned short ent[1040];
    __shared__ float rrow[H_SZ];
    const int tid = threadIdx.x;
    const int jcc = tid * 4;

    if (tid < 32) f[tid] = flags[blockIdx.x + tid * 256];
    __syncthreads();

    for (int i = 0; i < 32; ++i) {
        if (!f[i]) continue;                     // uniform (LDS broadcast)
        const int r = blockIdx.x + i * 256;
        if (tid == 0) { cnt = 0; tot = 0; }
        __syncthreads();

        const unsigned kw2 = *(const unsigned*)(kb + (size_t)r * H_SZ + jcc);
        const f32x4 b2q = *(const f32x4*)&b2[jcc];
        if (kw2) {
            #pragma unroll
            for (int u = 0; u < 4; ++u) {
                const unsigned ku = (kw2 >> (8 * u)) & 0xffu;
                if (ku) {
                    const int p = atomicAdd(&cnt, 1);
                    ent[p] = (unsigned short)((jcc + u) | (ku << 12));
                }
            }
        }
        __syncthreads();
        const int n = cnt;
        if (tid == 0 && (n & 1))                 // pad to even (k=1, zero row: adds 0)
            ent[n] = (unsigned short)(H_SZ | (1u << 12));
        __syncthreads();
        const int e3 = __builtin_amdgcn_readfirstlane((n + 1) & ~1);

        f32x4 v2 = {0,0,0,0};
        int c0 = 0, c1 = 0, c2 = 0, c3 = 0;
        { f32x4 i2 = b2q; TPASS(1)  STEP }
        { f32x4 i2 = b2q; TPASS(2)  STEP }
        { f32x4 i2 = b2q; TPASS(3)  STEP }
        { f32x4 i2 = b2q; TPASS(4)  STEP }
        { f32x4 i2 = b2q; TPASS(5)  STEP }
        { f32x4 i2 = b2q; TPASS(6)  STEP }
        { f32x4 i2 = b2q; TPASS(7)  STEP }
        { f32x4 i2 = b2q; TPASS(8)  STEP }
        { f32x4 i2 = b2q; TPASS(9)  STEP }
        { f32x4 i2 = b2q; TPASS(10) STEP }
        { f32x4 i2 = b2q; TPASS(11) STEP }
        { f32x4 i2 = b2q; TPASS(12) STEP }
        { f32x4 i2 = b2q; TPASS(13) STEP }
        { f32x4 i2 = b2q; TPASS(14) STEP }
        { f32x4 i2 = b2q; TPASS(15) STEP }

        const int my = c0 + c1 + c2 + c3;
        if (my) atomicAdd(&tot, my);
        __syncthreads();

        if (tot == 0) {
            if (tid < D_OUT) out[(size_t)r * D_OUT + tid] = bout[tid];
        } else {
            rrow[jcc + 0] = (float)c0 / 15.0f;
            rrow[jcc + 1] = (float)c1 / 15.0f;
            rrow[jcc + 2] = (float)c2 / 15.0f;
            rrow[jcc + 3] = (float)c3 / 15.0f;
            __syncthreads();
            if (tid < D_OUT) {
                float a = bout[tid];
                const float* wrow = Wout + (size_t)tid * H_SZ;
                for (int j = 0; j < H_SZ; ++j) a = fmaf(rrow[j], wrow[j], a);
                out[(size_t)r * D_OUT + tid] = a;
            }
        }
        __syncthreads();                         // before LDS reuse next iteration
    }
}

// ---------------------------------------------------------------- launch
extern "C" void kernel_launch(void* const* d_in, const int* in_sizes, int n_in,
                              void* d_out, int out_size, void* d_ws, size_t ws_size,
                              hipStream_t stream) {
    const float* x    = (const float*)d_in[0];
    const float* W1   = (const float*)d_in[1];
    const float* b1   = (const float*)d_in[2];
    const float* W2   = (const float*)d_in[3];
    const float* b2   = (const float*)d_in[4];
    const float* Wout = (const float*)d_in[5];
    const float* bout = (const float*)d_in[6];
    float* out = (float*)d_out;

    char* ws = (char*)d_ws;
    unsigned short* W2cb  = (unsigned short*)(ws);              // 2 MB + 2 KB pad row
    int*            flags = (int*)(ws + (4 << 20));             // 32 KB
    unsigned char*  kbuf  = (unsigned char*)(ws + (8 << 20));   // 8 MB intervals

    k0_transpose<<<dim3(H_SZ / 32, H_SZ / 32), dim3(32, 8), 0, stream>>>(W2, W2cb, flags);
    k1_mfma<<<dim3(B_SZ / 128, H_SZ / 128), 256, 0, stream>>>(x, W1, b1, kbuf);
    k2_cert<<<B_SZ, 256, 0, stream>>>(kbuf, W2cb, b2, bout, flags, out);
    k3_rare<<<256, 256, 0, stream>>>(kbuf, W2cb, b2, Wout, bout, flags, out);
}

// Round 16
// 84.729 us; speedup vs baseline: 1.5986x; 1.5986x over previous
//
#include <hip/hip_runtime.h>
#include <hip/hip_bf16.h>

// SpikingPolicyNet: B=8192, D_in=256, H=1024, D_out=64, T=15, TAU=20, V_TH=1
//
// Pipeline:
//  K0 : W2 -> W2cb (bf16 W2^T, row 1024 zeroed = sentinel for padded entries)
//  K1 : bf16-MFMA x@W1.T; epilogue folds b1 and emits the closed-form spike
//       interval k = ceil(log2(1-1/I)/log2(0.95)) as byte plane kb[b][j]
//       (spikes at t = k,2k,...; I1 time-invariant).
//  K2 : block-per-row, EXACT (no certificate, no rare path). R10's proven
//       bucket-gather skeleton, reduced to 8 buckets (k=8..15) with signed
//       register sums G8..G15; k<=7 spikers (~0.5/row) go to a small flat
//       list consumed inside the time loop. Exact recurrence: for t>=8 the
//       only divisor >=8 of t is t itself, so
//         I2_t = b2 + [small-k divisor terms] + G_t   (G_t = static register)
//       15 unrolled steps, divmask-predicated small loads (usually 0-trip).
//       Spike counts -> block fast path out = bout (bit-exact when no s2
//       spikes; absmax==0 in R1-R15 incl full-fp32 R1) else inline GEMV.

#define B_SZ   8192
#define D_IN   256
#define H_SZ   1024
#define D_OUT  64
#define T_STEPS 15

typedef __attribute__((ext_vector_type(8))) short short8;
typedef __attribute__((ext_vector_type(4))) float f32x4;

static __device__ __forceinline__ unsigned int pk_bf16(float lo, float hi) {
    return (__builtin_bit_cast(unsigned int, hi) & 0xffff0000u) |
           (__builtin_bit_cast(unsigned int, lo) >> 16);
}
static __device__ __forceinline__ f32x4 unp4(uint2 w) {
    f32x4 r;
    r.x = __builtin_bit_cast(float, w.x << 16);
    r.y = __builtin_bit_cast(float, w.x & 0xffff0000u);
    r.z = __builtin_bit_cast(float, w.y << 16);
    r.w = __builtin_bit_cast(float, w.y & 0xffff0000u);
    return r;
}
__host__ __device__ constexpr unsigned divmask(int t) {   // bit k set iff k | t
    unsigned m = 0;
    for (int k = 1; k <= 15; ++k) if (t % k == 0) m |= 1u << k;
    return m;
}

// ---------------------------------------------------------------- K0: W2 -> W2cb (+zero pad row)
__global__ __launch_bounds__(256) void k0_transpose(const float* __restrict__ W2,
                                                    unsigned short* __restrict__ W2cb) {
    __shared__ float tile[32][33];
    const int bx = blockIdx.x * 32;
    const int by = blockIdx.y * 32;
    const int tx = threadIdx.x;
    const int ty = threadIdx.y;
    #pragma unroll
    for (int i = ty; i < 32; i += 8)
        tile[i][tx] = W2[(by + i) * H_SZ + bx + tx];
    __syncthreads();
    #pragma unroll
    for (int i = ty; i < 32; i += 8)
        W2cb[(size_t)(bx + i) * H_SZ + by + tx] =
            (unsigned short)(__builtin_bit_cast(unsigned int, tile[tx][i]) >> 16);
    if (blockIdx.x == 0 && blockIdx.y == 0) {                   // zero sentinel row 1024
        const int t = ty * 32 + tx;
        #pragma unroll
        for (int i = 0; i < 4; ++i)
            W2cb[(size_t)H_SZ * H_SZ + i * 256 + t] = 0;
    }
}

// ---------------------------------------------------------------- K1: interval byte-plane from x@W1.T+b1
__global__ __launch_bounds__(256) void k1_mfma(const float* __restrict__ A,
                                               const float* __restrict__ Bw,
                                               const float* __restrict__ b1,
                                               unsigned char* __restrict__ kb) {
    __shared__ unsigned int As4[2048];   // 128 rows x 32 bf16, 16B-chunk XOR swizzle
    __shared__ unsigned int Bs4[2048];
    const int tid  = threadIdx.x;
    const int m0   = blockIdx.x * 128;
    const int n0   = blockIdx.y * 128;
    const int lane = tid & 63;
    const int wid  = tid >> 6;
    const int wr   = wid >> 1, wc = wid & 1;

    const int row0 = tid >> 2;
    const int row1 = row0 + 64;
    const int q0   = tid & 3;

    f32x4 acc[4][4] = {};
    float4 s0[8], s1[8];

    auto LOAD = [&](float4* s, int kbk) {
        const float* pa0 = A  + (m0 + row0) * D_IN + kbk + q0 * 8;
        const float* pa1 = A  + (m0 + row1) * D_IN + kbk + q0 * 8;
        const float* pb0 = Bw + (n0 + row0) * D_IN + kbk + q0 * 8;
        const float* pb1 = Bw + (n0 + row1) * D_IN + kbk + q0 * 8;
        s[0] = *(const float4*)pa0; s[1] = *(const float4*)(pa0 + 4);
        s[2] = *(const float4*)pa1; s[3] = *(const float4*)(pa1 + 4);
        s[4] = *(const float4*)pb0; s[5] = *(const float4*)(pb0 + 4);
        s[6] = *(const float4*)pb1; s[7] = *(const float4*)(pb1 + 4);
    };
    auto WRITE = [&](const float4* s) {
        const int i0 = row0 * 16 + (q0 ^ ((row0 >> 1) & 3)) * 4;
        const int i1 = row1 * 16 + (q0 ^ ((row1 >> 1) & 3)) * 4;
        *(uint4*)&As4[i0] = make_uint4(pk_bf16(s[0].x, s[0].y), pk_bf16(s[0].z, s[0].w),
                                       pk_bf16(s[1].x, s[1].y), pk_bf16(s[1].z, s[1].w));
        *(uint4*)&As4[i1] = make_uint4(pk_bf16(s[2].x, s[2].y), pk_bf16(s[2].z, s[2].w),
                                       pk_bf16(s[3].x, s[3].y), pk_bf16(s[3].z, s[3].w));
        *(uint4*)&Bs4[i0] = make_uint4(pk_bf16(s[4].x, s[4].y), pk_bf16(s[4].z, s[4].w),
                                       pk_bf16(s[5].x, s[5].y), pk_bf16(s[5].z, s[5].w));
        *(uint4*)&Bs4[i1] = make_uint4(pk_bf16(s[6].x, s[6].y), pk_bf16(s[6].z, s[6].w),
                                       pk_bf16(s[7].x, s[7].y), pk_bf16(s[7].z, s[7].w));
    };
    auto COMPUTE = [&]() {
        short8 afr[4], bfr[4];
        const int q  = lane >> 4;
        const int lr = lane & 15;
        #pragma unroll
        for (int mf = 0; mf < 4; ++mf) {
            const int ra = wr * 64 + mf * 16 + lr;
            afr[mf] = *(const short8*)&As4[ra * 16 + (q ^ ((ra >> 1) & 3)) * 4];
            const int rb = wc * 64 + mf * 16 + lr;
            bfr[mf] = *(const short8*)&Bs4[rb * 16 + (q ^ ((rb >> 1) & 3)) * 4];
        }
        #pragma unroll
        for (int mf = 0; mf < 4; ++mf)
            #pragma unroll
            for (int nf = 0; nf < 4; ++nf)
                acc[mf][nf] = __builtin_amdgcn_mfma_f32_16x16x32_bf16(
                    afr[mf], bfr[nf], acc[mf][nf], 0, 0, 0);
    };

    LOAD(s0, 0);
    for (int kk = 0; kk < D_IN; kk += 64) {
        if (kk + 32 < D_IN) LOAD(s1, kk + 32);
        __syncthreads();
        WRITE(s0);
        __syncthreads();
        COMPUTE();
        if (kk + 64 < D_IN) LOAD(s0, kk + 64);
        __syncthreads();
        WRITE(s1);
        __syncthreads();
        COMPUTE();
    }

    // Epilogue: I = acc + b1[col]; k = ceil(log2(1-1/I)*-13.5134035), 0 = none.
    const int lr = lane & 15;
    const int qq = lane >> 4;
    float b1v[4];
    #pragma unroll
    for (int nf = 0; nf < 4; ++nf) b1v[nf] = b1[n0 + wc * 64 + nf * 16 + lr];

    #pragma unroll
    for (int mf = 0; mf < 4; ++mf) {
        const int rbase = m0 + wr * 64 + mf * 16 + qq * 4;
        #pragma unroll
        for (int nf = 0; nf < 4; ++nf) {
            const int c = n0 + wc * 64 + nf * 16 + lr;
            #pragma unroll
            for (int r = 0; r < 4; ++r) {
                const float I = acc[mf][nf][r] + b1v[nf];
                int k = 0;
                if (I > 1.8632055f) {
                    const float l2 = __builtin_amdgcn_logf(1.0f - __builtin_amdgcn_rcpf(I));
                    int kc = (int)__builtin_ceilf(l2 * -13.5134035f);
                    k = kc < 1 ? 1 : (kc > 15 ? 15 : kc);
                }
                kb[(size_t)(rbase + r) * H_SZ + c] = (unsigned char)k;
            }
        }
    }
}

// ---------------------------------------------------------------- K2: exact 8-bucket gather + recurrence
// one quad of big-bucket entries -> 4 signed adds into a STATIC register
#define BQ(IDX, GV)                                                           \
    { const uint2 eq = *(const uint2*)&ent[IDX];                              \
      const unsigned sa = (unsigned)__builtin_amdgcn_readfirstlane((int)eq.x);\
      const unsigned sb = (unsigned)__builtin_amdgcn_readfirstlane((int)eq.y);\
      const uint2 qa = *(const uint2*)(W2cb + ((size_t)(sa & 0xffffu) << 10) + jc); \
      const uint2 qb = *(const uint2*)(W2cb + ((size_t)(sa >> 16) << 10) + jc);     \
      const uint2 qc = *(const uint2*)(W2cb + ((size_t)(sb & 0xffffu) << 10) + jc); \
      const uint2 qd = *(const uint2*)(W2cb + ((size_t)(sb >> 16) << 10) + jc);     \
      GV += unp4(qa); GV += unp4(qb); GV += unp4(qc); GV += unp4(qd); }

#define BLOOP(GV, R)                                                          \
    for (int i = stt[R]; i < stt[(R) + 1]; i += 4) BQ(i, GV)

// small-k divisor terms for step t (nsm ~ 0-2, wave-uniform trip count)
#define SMALLT(T)                                                             \
    { constexpr unsigned dm = divmask(T);                                     \
      for (int i = 0; i < nsm; ++i) {                                         \
          const int ee = __builtin_amdgcn_readfirstlane((int)ent[i]);         \
          if ((dm >> (ee >> 12)) & 1) {                                       \
              const uint2 w = *(const uint2*)(W2cb + ((size_t)(ee & 0xfffu) << 10) + jc); \
              i2 += unp4(w); } } }

#define STEP                                                                  \
    { v2 = v2 * 0.95f + i2 * 0.05f;                                           \
      if (v2.x > 1.0f) { v2.x = 0.f; ++c0; }                                  \
      if (v2.y > 1.0f) { v2.y = 0.f; ++c1; }                                  \
      if (v2.z > 1.0f) { v2.z = 0.f; ++c2; }                                  \
      if (v2.w > 1.0f) { v2.w = 0.f; ++c3; } }

__global__ __launch_bounds__(256, 4) void k2_snn(const unsigned char* __restrict__ kb,
                                                 const unsigned short* __restrict__ W2cb,
                                                 const float* __restrict__ b2,
                                                 const float* __restrict__ Wout,
                                                 const float* __restrict__ bout,
                                                 float* __restrict__ out) {
    const int b   = blockIdx.x;
    const int tid = threadIdx.x;
    const int jc  = tid * 4;

    __shared__ int cnt[16];                  // [0] = small (k<=7), [8..15] = big
    __shared__ int curs[16];
    __shared__ int stb[9];                   // big-bucket starts (r=0..7 <-> k=8..15) + end
    __shared__ int tot;
    __shared__ __align__(8) unsigned short ent[1064];  // small flat @0; big buckets padded x4
    __shared__ float rrow[H_SZ];

    if (tid < 16) { cnt[tid] = 0; if (tid == 0) tot = 0; }
    const unsigned int kw = *(const unsigned int*)(kb + (size_t)b * H_SZ + jc);
    const f32x4 b2q = *(const f32x4*)&b2[jc];
    __syncthreads();

    if (kw) {
        #pragma unroll
        for (int u = 0; u < 4; ++u) {
            const unsigned int ku = (kw >> (8 * u)) & 0xffu;
            if (ku) atomicAdd(&cnt[(ku >= 8) ? (int)ku : 0], 1);
        }
    }
    __syncthreads();
    if (tid < 9) {                           // parallel prefix over 8 big buckets
        int s = (cnt[0] + 3) & ~3;           // small region [0, cnt[0]), gap to x4
        for (int r = 0; r < tid; ++r) s += (cnt[8 + r] + 3) & ~3;
        stb[tid] = s;
        if (tid < 8) curs[8 + tid] = s;
        if (tid == 0) curs[0] = 0;
    }
    __syncthreads();
    if (kw) {                                // scatter (small: j|k<<12; big: plain j)
        #pragma unroll
        for (int u = 0; u < 4; ++u) {
            const unsigned int ku = (kw >> (8 * u)) & 0xffu;
            if (ku) {
                if (ku >= 8) {
                    const int p = atomicAdd(&curs[ku], 1);
                    ent[p] = (unsigned short)(jc + u);
                } else {
                    const int p = atomicAdd(&curs[0], 1);
                    ent[p] = (unsigned short)((jc + u) | (ku << 12));
                }
            }
        }
    }
    if (tid < 8) {                           // sentinel-pad big-bucket tails (zero row)
        for (int p = stb[tid] + cnt[8 + tid]; p < stb[tid + 1]; ++p)
            ent[p] = (unsigned short)H_SZ;
    }
    __syncthreads();

    int stt[9];
    #pragma unroll
    for (int r = 0; r < 9; ++r) stt[r] = __builtin_amdgcn_readfirstlane(stb[r]);
    const int nsm = __builtin_amdgcn_readfirstlane(cnt[0]);

    // ---- gather: 8 bucket loops, signed sums into static registers (R10 shape)
    f32x4 G8 = {0,0,0,0}, G9 = {0,0,0,0}, G10 = {0,0,0,0}, G11 = {0,0,0,0};
    f32x4 G12 = {0,0,0,0}, G13 = {0,0,0,0}, G14 = {0,0,0,0}, G15 = {0,0,0,0};
    BLOOP(G8, 0)  BLOOP(G9, 1)  BLOOP(G10, 2) BLOOP(G11, 3)
    BLOOP(G12, 4) BLOOP(G13, 5) BLOOP(G14, 6) BLOOP(G15, 7)

    // ---- exact recurrence: I2_t = b2 + small(t) + (t>=8 ? G_t : 0)
    f32x4 v2 = {0,0,0,0};
    int c0 = 0, c1 = 0, c2 = 0, c3 = 0;
    { f32x4 i2 = b2q;       SMALLT(1)  STEP }
    { f32x4 i2 = b2q;       SMALLT(2)  STEP }
    { f32x4 i2 = b2q;       SMALLT(3)  STEP }
    { f32x4 i2 = b2q;       SMALLT(4)  STEP }
    { f32x4 i2 = b2q;       SMALLT(5)  STEP }
    { f32x4 i2 = b2q;       SMALLT(6)  STEP }
    { f32x4 i2 = b2q;       SMALLT(7)  STEP }
    { f32x4 i2 = b2q + G8;  SMALLT(8)  STEP }
    { f32x4 i2 = b2q + G9;  SMALLT(9)  STEP }
    { f32x4 i2 = b2q + G10; SMALLT(10) STEP }
    { f32x4 i2 = b2q + G11; SMALLT(11) STEP }
    { f32x4 i2 = b2q + G12; SMALLT(12) STEP }
    { f32x4 i2 = b2q + G13; SMALLT(13) STEP }
    { f32x4 i2 = b2q + G14; SMALLT(14) STEP }
    { f32x4 i2 = b2q + G15; SMALLT(15) STEP }

    // ---- readout
    const int my = c0 + c1 + c2 + c3;
    if (my) atomicAdd(&tot, my);
    __syncthreads();

    if (tot == 0) {                          // no s2 spikes: out = bout (bit-exact)
        if (tid < D_OUT) out[(size_t)b * D_OUT + tid] = bout[tid];
        return;
    }

    rrow[jc + 0] = (float)c0 / 15.0f;
    rrow[jc + 1] = (float)c1 / 15.0f;
    rrow[jc + 2] = (float)c2 / 15.0f;
    rrow[jc + 3] = (float)c3 / 15.0f;
    __syncthreads();
    if (tid < D_OUT) {
        float a = bout[tid];
        const float* wrow = Wout + (size_t)tid * H_SZ;
        for (int j = 0; j < H_SZ; ++j) a = fmaf(rrow[j], wrow[j], a);
        out[(size_t)b * D_OUT + tid] = a;
    }
}

// ---------------------------------------------------------------- launch
extern "C" void kernel_launch(void* const* d_in, const int* in_sizes, int n_in,
                              void* d_out, int out_size, void* d_ws, size_t ws_size,
                              hipStream_t stream) {
    const float* x    = (const float*)d_in[0];
    const float* W1   = (const float*)d_in[1];
    const float* b1   = (const float*)d_in[2];
    const float* W2   = (const float*)d_in[3];
    const float* b2   = (const float*)d_in[4];
    const float* Wout = (const float*)d_in[5];
    const float* bout = (const float*)d_in[6];
    float* out = (float*)d_out;

    char* ws = (char*)d_ws;
    unsigned short* W2cb = (unsigned short*)(ws);              // 2 MB + 2 KB pad row
    unsigned char*  kbuf = (unsigned char*)(ws + (8 << 20));   // 8 MB intervals

    k0_transpose<<<dim3(H_SZ / 32, H_SZ / 32), dim3(32, 8), 0, stream>>>(W2, W2cb);
    k1_mfma<<<dim3(B_SZ / 128, H_SZ / 128), 256, 0, stream>>>(x, W1, b1, kbuf);
    k2_snn<<<B_SZ, 256, 0, stream>>>(kbuf, W2cb, b2, Wout, bout, out);
}

// Round 17
// 68.420 us; speedup vs baseline: 1.9796x; 1.2384x over previous
//
#include <hip/hip_runtime.h>
#include <hip/hip_bf16.h>

// SpikingPolicyNet: B=8192, D_in=256, H=1024, D_out=64, T=15, TAU=20, V_TH=1
//
// Pipeline:
//  K0 : W2 -> W2cb (bf16 W2^T, row 1024 zeroed = sentinel); zero flags[8192].
//  K1 : bf16-MFMA x@W1.T; epilogue folds b1, emits closed-form spike interval
//       k = ceil(log2(1-1/I)/log2(0.95)) as byte plane kb[b][j] (spikes at
//       t = k,2k,...; I1 time-invariant).
//  K2 : R8-proven flat-list 8-deep gather (~3.5us for all 8192 rows) with a
//       DECAY-WEIGHTED certificate:
//         v2_t = 0.05*sum_{s<=t} 0.95^(t-s) I2_s   (no-reset upper bound;
//         resets only lower v2) and I2_s <= relu(b2) + sum_j relu(w_j)[k_j|s]
//         => v2_t <= 0.537*relu(b2) + sum_j coef(k_j)*relu(w_j),
//         coef(k) = 0.05*max_t sum_{m:mk<=t} 0.95^(t-mk)  (=0.05 for k>=8).
//       Table stores coef(k-1) to absorb +-1 k-flips; threshold 0.98 absorbs
//       bf16 slack. Cert <= 0.98 proves zero s2 spikes -> out = bout
//       (bit-exact; absmax==0 R1-R16 incl full-fp32 R1). Fail -> flags[b]=1.
//  K3 : per-row flag gate; flagged rows (expected 0) run R16's proven exact
//       8-bucket G-register recurrence (~4us/row) and overwrite out[row].

#define B_SZ   8192
#define D_IN   256
#define H_SZ   1024
#define D_OUT  64
#define T_STEPS 15
#define CERT_THR 0.98f

typedef __attribute__((ext_vector_type(8))) short short8;
typedef __attribute__((ext_vector_type(4))) float f32x4;

__device__ __constant__ float CTAB[16] = {   // CTAB[k] = coef(k-1), k-flip robust
    0.05f,     0.53670f, 0.53670f, 0.26271f, 0.18815f, 0.12390f, 0.11863f,
    0.086755f, 0.084882f, 0.05f,   0.05f,    0.05f,    0.05f,    0.05f,
    0.05f,     0.05f};

static __device__ __forceinline__ unsigned int pk_bf16(float lo, float hi) {
    return (__builtin_bit_cast(unsigned int, hi) & 0xffff0000u) |
           (__builtin_bit_cast(unsigned int, lo) >> 16);
}
static __device__ __forceinline__ f32x4 unp4(uint2 w) {
    f32x4 r;
    r.x = __builtin_bit_cast(float, w.x << 16);
    r.y = __builtin_bit_cast(float, w.x & 0xffff0000u);
    r.z = __builtin_bit_cast(float, w.y << 16);
    r.w = __builtin_bit_cast(float, w.y & 0xffff0000u);
    return r;
}
static __device__ __forceinline__ f32x4 relu4(f32x4 a) {
    a.x = fmaxf(a.x, 0.f); a.y = fmaxf(a.y, 0.f);
    a.z = fmaxf(a.z, 0.f); a.w = fmaxf(a.w, 0.f);
    return a;
}

// ---------------------------------------------------------------- K0: W2 -> W2cb (+pad) + flags reset
__global__ __launch_bounds__(256) void k0_transpose(const float* __restrict__ W2,
                                                    unsigned short* __restrict__ W2cb,
                                                    int* __restrict__ flags) {
    __shared__ float tile[32][33];
    const int bx = blockIdx.x * 32;
    const int by = blockIdx.y * 32;
    const int tx = threadIdx.x;
    const int ty = threadIdx.y;
    #pragma unroll
    for (int i = ty; i < 32; i += 8)
        tile[i][tx] = W2[(by + i) * H_SZ + bx + tx];
    __syncthreads();
    #pragma unroll
    for (int i = ty; i < 32; i += 8)
        W2cb[(size_t)(bx + i) * H_SZ + by + tx] =
            (unsigned short)(__builtin_bit_cast(unsigned int, tile[tx][i]) >> 16);
    if (blockIdx.x == 0 && blockIdx.y == 0) {                   // zero sentinel row 1024
        const int t = ty * 32 + tx;
        #pragma unroll
        for (int i = 0; i < 4; ++i)
            W2cb[(size_t)H_SZ * H_SZ + i * 256 + t] = 0;
    }
    const int lb = blockIdx.y * 32 + blockIdx.x;                 // zero flags[8192]
    if (lb < 32) flags[lb * 256 + ty * 32 + tx] = 0;
}

// ---------------------------------------------------------------- K1: interval byte-plane from x@W1.T+b1
__global__ __launch_bounds__(256) void k1_mfma(const float* __restrict__ A,
                                               const float* __restrict__ Bw,
                                               const float* __restrict__ b1,
                                               unsigned char* __restrict__ kb) {
    __shared__ unsigned int As4[2048];   // 128 rows x 32 bf16, 16B-chunk XOR swizzle
    __shared__ unsigned int Bs4[2048];
    const int tid  = threadIdx.x;
    const int m0   = blockIdx.x * 128;
    const int n0   = blockIdx.y * 128;
    const int lane = tid & 63;
    const int wid  = tid >> 6;
    const int wr   = wid >> 1, wc = wid & 1;

    const int row0 = tid >> 2;
    const int row1 = row0 + 64;
    const int q0   = tid & 3;

    f32x4 acc[4][4] = {};
    float4 s0[8], s1[8];

    auto LOAD = [&](float4* s, int kbk) {
        const float* pa0 = A  + (m0 + row0) * D_IN + kbk + q0 * 8;
        const float* pa1 = A  + (m0 + row1) * D_IN + kbk + q0 * 8;
        const float* pb0 = Bw + (n0 + row0) * D_IN + kbk + q0 * 8;
        const float* pb1 = Bw + (n0 + row1) * D_IN + kbk + q0 * 8;
        s[0] = *(const float4*)pa0; s[1] = *(const float4*)(pa0 + 4);
        s[2] = *(const float4*)pa1; s[3] = *(const float4*)(pa1 + 4);
        s[4] = *(const float4*)pb0; s[5] = *(const float4*)(pb0 + 4);
        s[6] = *(const float4*)pb1; s[7] = *(const float4*)(pb1 + 4);
    };
    auto WRITE = [&](const float4* s) {
        const int i0 = row0 * 16 + (q0 ^ ((row0 >> 1) & 3)) * 4;
        const int i1 = row1 * 16 + (q0 ^ ((row1 >> 1) & 3)) * 4;
        *(uint4*)&As4[i0] = make_uint4(pk_bf16(s[0].x, s[0].y), pk_bf16(s[0].z, s[0].w),
                                       pk_bf16(s[1].x, s[1].y), pk_bf16(s[1].z, s[1].w));
        *(uint4*)&As4[i1] = make_uint4(pk_bf16(s[2].x, s[2].y), pk_bf16(s[2].z, s[2].w),
                                       pk_bf16(s[3].x, s[3].y), pk_bf16(s[3].z, s[3].w));
        *(uint4*)&Bs4[i0] = make_uint4(pk_bf16(s[4].x, s[4].y), pk_bf16(s[4].z, s[4].w),
                                       pk_bf16(s[5].x, s[5].y), pk_bf16(s[5].z, s[5].w));
        *(uint4*)&Bs4[i1] = make_uint4(pk_bf16(s[6].x, s[6].y), pk_bf16(s[6].z, s[6].w),
                                       pk_bf16(s[7].x, s[7].y), pk_bf16(s[7].z, s[7].w));
    };
    auto COMPUTE = [&]() {
        short8 afr[4], bfr[4];
        const int q  = lane >> 4;
        const int lr = lane & 15;
        #pragma unroll
        for (int mf = 0; mf < 4; ++mf) {
            const int ra = wr * 64 + mf * 16 + lr;
            afr[mf] = *(const short8*)&As4[ra * 16 + (q ^ ((ra >> 1) & 3)) * 4];
            const int rb = wc * 64 + mf * 16 + lr;
            bfr[mf] = *(const short8*)&Bs4[rb * 16 + (q ^ ((rb >> 1) & 3)) * 4];
        }
        #pragma unroll
        for (int mf = 0; mf < 4; ++mf)
            #pragma unroll
            for (int nf = 0; nf < 4; ++nf)
                acc[mf][nf] = __builtin_amdgcn_mfma_f32_16x16x32_bf16(
                    afr[mf], bfr[nf], acc[mf][nf], 0, 0, 0);
    };

    LOAD(s0, 0);
    for (int kk = 0; kk < D_IN; kk += 64) {
        if (kk + 32 < D_IN) LOAD(s1, kk + 32);
        __syncthreads();
        WRITE(s0);
        __syncthreads();
        COMPUTE();
        if (kk + 64 < D_IN) LOAD(s0, kk + 64);
        __syncthreads();
        WRITE(s1);
        __syncthreads();
        COMPUTE();
    }

    // Epilogue: I = acc + b1[col]; k = ceil(log2(1-1/I)*-13.5134035), 0 = none.
    const int lr = lane & 15;
    const int qq = lane >> 4;
    float b1v[4];
    #pragma unroll
    for (int nf = 0; nf < 4; ++nf) b1v[nf] = b1[n0 + wc * 64 + nf * 16 + lr];

    #pragma unroll
    for (int mf = 0; mf < 4; ++mf) {
        const int rbase = m0 + wr * 64 + mf * 16 + qq * 4;
        #pragma unroll
        for (int nf = 0; nf < 4; ++nf) {
            const int c = n0 + wc * 64 + nf * 16 + lr;
            #pragma unroll
            for (int r = 0; r < 4; ++r) {
                const float I = acc[mf][nf][r] + b1v[nf];
                int k = 0;
                if (I > 1.8632055f) {
                    const float l2 = __builtin_amdgcn_logf(1.0f - __builtin_amdgcn_rcpf(I));
                    int kc = (int)__builtin_ceilf(l2 * -13.5134035f);
                    k = kc < 1 ? 1 : (kc > 15 ? 15 : kc);
                }
                kb[(size_t)(rbase + r) * H_SZ + c] = (unsigned char)k;
            }
        }
    }
}

// ---------------------------------------------------------------- K2: flat-list decay-weighted cert (R8 shape)
#define PADE ((unsigned)(H_SZ | (15u << 16)))

__global__ __launch_bounds__(256) void k2_cert(const unsigned char* __restrict__ kb,
                                               const unsigned short* __restrict__ W2cb,
                                               const float* __restrict__ b2,
                                               const float* __restrict__ bout,
                                               int* __restrict__ flags,
                                               float* __restrict__ out) {
    const int b   = blockIdx.x;
    const int tid = threadIdx.x;
    const int jc  = tid * 4;

    __shared__ unsigned int list[1032];
    __shared__ float coefl[16];
    __shared__ int cnt;

    if (tid == 0) cnt = 0;
    if (tid < 16) coefl[tid] = CTAB[tid];

    const unsigned int kw = *(const unsigned int*)(kb + (size_t)b * H_SZ + jc);
    const f32x4 b2q = *(const f32x4*)&b2[jc];
    __syncthreads();

    if (kw) {
        #pragma unroll
        for (int u = 0; u < 4; ++u) {
            const unsigned ku = (kw >> (8 * u)) & 0xffu;
            if (ku) {
                const int p = atomicAdd(&cnt, 1);
                list[p] = (unsigned)(jc + u) | (ku << 16);
            }
        }
    }
    __syncthreads();
    const int n = cnt;

    f32x4 U = 0.53670f * relu4(b2q);
    for (int s = 0; s < n; s += 8) {
        const uint4 ea = *(const uint4*)&list[s];        // broadcast LDS reads
        const uint4 eb = *(const uint4*)&list[s + 4];
        const unsigned e0 = ea.x;                         // s+0 < n guaranteed
        const unsigned e1 = (s + 1 < n) ? ea.y : PADE;    // pad -> zero row, cf*0
        const unsigned e2 = (s + 2 < n) ? ea.z : PADE;
        const unsigned e3 = (s + 3 < n) ? ea.w : PADE;
        const unsigned e4 = (s + 4 < n) ? eb.x : PADE;
        const unsigned e5 = (s + 5 < n) ? eb.y : PADE;
        const unsigned e6 = (s + 6 < n) ? eb.z : PADE;
        const unsigned e7 = (s + 7 < n) ? eb.w : PADE;
        const uint2 w0 = *(const uint2*)(W2cb + ((size_t)(e0 & 0xffffu) << 10) + jc);
        const uint2 w1 = *(const uint2*)(W2cb + ((size_t)(e1 & 0xffffu) << 10) + jc);
        const uint2 w2 = *(const uint2*)(W2cb + ((size_t)(e2 & 0xffffu) << 10) + jc);
        const uint2 w3 = *(const uint2*)(W2cb + ((size_t)(e3 & 0xffffu) << 10) + jc);
        const uint2 w4 = *(const uint2*)(W2cb + ((size_t)(e4 & 0xffffu) << 10) + jc);
        const uint2 w5 = *(const uint2*)(W2cb + ((size_t)(e5 & 0xffffu) << 10) + jc);
        const uint2 w6 = *(const uint2*)(W2cb + ((size_t)(e6 & 0xffffu) << 10) + jc);
        const uint2 w7 = *(const uint2*)(W2cb + ((size_t)(e7 & 0xffffu) << 10) + jc);
        U += coefl[e0 >> 16] * relu4(unp4(w0));
        U += coefl[e1 >> 16] * relu4(unp4(w1));
        U += coefl[e2 >> 16] * relu4(unp4(w2));
        U += coefl[e3 >> 16] * relu4(unp4(w3));
        U += coefl[e4 >> 16] * relu4(unp4(w4));
        U += coefl[e5 >> 16] * relu4(unp4(w5));
        U += coefl[e6 >> 16] * relu4(unp4(w6));
        U += coefl[e7 >> 16] * relu4(unp4(w7));
    }

    if ((U.x > CERT_THR) || (U.y > CERT_THR) || (U.z > CERT_THR) || (U.w > CERT_THR))
        flags[b] = 1;                        // racy same-value store: benign

    if (tid < D_OUT) out[(size_t)b * D_OUT + tid] = bout[tid];   // k3 overwrites if flagged
}

// ---------------------------------------------------------------- K3: exact recurrence for flagged rows
#define BQ(IDX, GV)                                                           \
    { const uint2 eq = *(const uint2*)&ent[IDX];                              \
      const unsigned sa = (unsigned)__builtin_amdgcn_readfirstlane((int)eq.x);\
      const unsigned sb = (unsigned)__builtin_amdgcn_readfirstlane((int)eq.y);\
      const uint2 qa = *(const uint2*)(W2cb + ((size_t)(sa & 0xffffu) << 10) + jc); \
      const uint2 qb = *(const uint2*)(W2cb + ((size_t)(sa >> 16) << 10) + jc);     \
      const uint2 qc = *(const uint2*)(W2cb + ((size_t)(sb & 0xffffu) << 10) + jc); \
      const uint2 qd = *(const uint2*)(W2cb + ((size_t)(sb >> 16) << 10) + jc);     \
      GV += unp4(qa); GV += unp4(qb); GV += unp4(qc); GV += unp4(qd); }

#define BLOOP(GV, R)                                                          \
    for (int i = stt[R]; i < stt[(R) + 1]; i += 4) BQ(i, GV)

__host__ __device__ constexpr unsigned divmask(int t) {   // bit k set iff k | t
    unsigned m = 0;
    for (int k = 1; k <= 15; ++k) if (t % k == 0) m |= 1u << k;
    return m;
}

#define SMALLT(T)                                                             \
    { constexpr unsigned dm = divmask(T);                                     \
      for (int i = 0; i < nsm; ++i) {                                         \
          const int ee = __builtin_amdgcn_readfirstlane((int)ent[i]);         \
          if ((dm >> (ee >> 12)) & 1) {                                       \
              const uint2 w = *(const uint2*)(W2cb + ((size_t)(ee & 0xfffu) << 10) + jc); \
              i2 += unp4(w); } } }

#define STEP                                                                  \
    { v2 = v2 * 0.95f + i2 * 0.05f;                                           \
      if (v2.x > 1.0f) { v2.x = 0.f; ++c0; }                                  \
      if (v2.y > 1.0f) { v2.y = 0.f; ++c1; }                                  \
      if (v2.z > 1.0f) { v2.z = 0.f; ++c2; }                                  \
      if (v2.w > 1.0f) { v2.w = 0.f; ++c3; } }

__global__ __launch_bounds__(256, 4) void k3_rare(const unsigned char* __restrict__ kb,
                                                  const unsigned short* __restrict__ W2cb,
                                                  const float* __restrict__ b2,
                                                  const float* __restrict__ Wout,
                                                  const float* __restrict__ bout,
                                                  const int* __restrict__ flags,
                                                  float* __restrict__ out) {
    const int b   = blockIdx.x;
    const int tid = threadIdx.x;
    const int jc  = tid * 4;

    if (flags[b] == 0) return;               // ~always (uniform early exit)

    __shared__ int cnt[16];                  // [0] = small (k<=7), [8..15] = big
    __shared__ int curs[16];
    __shared__ int stb[9];
    __shared__ int tot;
    __shared__ __align__(8) unsigned short ent[1064];
    __shared__ float rrow[H_SZ];

    if (tid < 16) { cnt[tid] = 0; if (tid == 0) tot = 0; }
    const unsigned int kw = *(const unsigned int*)(kb + (size_t)b * H_SZ + jc);
    const f32x4 b2q = *(const f32x4*)&b2[jc];
    __syncthreads();

    if (kw) {
        #pragma unroll
        for (int u = 0; u < 4; ++u) {
            const unsigned int ku = (kw >> (8 * u)) & 0xffu;
            if (ku) atomicAdd(&cnt[(ku >= 8) ? (int)ku : 0], 1);
        }
    }
    __syncthreads();
    if (tid < 9) {
        int s = (cnt[0] + 3) & ~3;
        for (int r = 0; r < tid; ++r) s += (cnt[8 + r] + 3) & ~3;
        stb[tid] = s;
        if (tid < 8) curs[8 + tid] = s;
        if (tid == 0) curs[0] = 0;
    }
    __syncthreads();
    if (kw) {
        #pragma unroll
        for (int u = 0; u < 4; ++u) {
            const unsigned int ku = (kw >> (8 * u)) & 0xffu;
            if (ku) {
                if (ku >= 8) {
                    const int p = atomicAdd(&curs[ku], 1);
                    ent[p] = (unsigned short)(jc + u);
                } else {
                    const int p = atomicAdd(&curs[0], 1);
                    ent[p] = (unsigned short)((jc + u) | (ku << 12));
                }
            }
        }
    }
    if (tid < 8) {
        for (int p = stb[tid] + cnt[8 + tid]; p < stb[tid + 1]; ++p)
            ent[p] = (unsigned short)H_SZ;
    }
    __syncthreads();

    int stt[9];
    #pragma unroll
    for (int r = 0; r < 9; ++r) stt[r] = __builtin_amdgcn_readfirstlane(stb[r]);
    const int nsm = __builtin_amdgcn_readfirstlane(cnt[0]);

    f32x4 G8 = {0,0,0,0}, G9 = {0,0,0,0}, G10 = {0,0,0,0}, G11 = {0,0,0,0};
    f32x4 G12 = {0,0,0,0}, G13 = {0,0,0,0}, G14 = {0,0,0,0}, G15 = {0,0,0,0};
    BLOOP(G8, 0)  BLOOP(G9, 1)  BLOOP(G10, 2) BLOOP(G11, 3)
    BLOOP(G12, 4) BLOOP(G13, 5) BLOOP(G14, 6) BLOOP(G15, 7)

    f32x4 v2 = {0,0,0,0};
    int c0 = 0, c1 = 0, c2 = 0, c3 = 0;
    { f32x4 i2 = b2q;       SMALLT(1)  STEP }
    { f32x4 i2 = b2q;       SMALLT(2)  STEP }
    { f32x4 i2 = b2q;       SMALLT(3)  STEP }
    { f32x4 i2 = b2q;       SMALLT(4)  STEP }
    { f32x4 i2 = b2q;       SMALLT(5)  STEP }
    { f32x4 i2 = b2q;       SMALLT(6)  STEP }
    { f32x4 i2 = b2q;       SMALLT(7)  STEP }
    { f32x4 i2 = b2q + G8;  SMALLT(8)  STEP }
    { f32x4 i2 = b2q + G9;  SMALLT(9)  STEP }
    { f32x4 i2 = b2q + G10; SMALLT(10) STEP }
    { f32x4 i2 = b2q + G11; SMALLT(11) STEP }
    { f32x4 i2 = b2q + G12; SMALLT(12) STEP }
    { f32x4 i2 = b2q + G13; SMALLT(13) STEP }
    { f32x4 i2 = b2q + G14; SMALLT(14) STEP }
    { f32x4 i2 = b2q + G15; SMALLT(15) STEP }

    const int my = c0 + c1 + c2 + c3;
    if (my) atomicAdd(&tot, my);
    __syncthreads();

    if (tot == 0) {
        if (tid < D_OUT) out[(size_t)b * D_OUT + tid] = bout[tid];
        return;
    }

    rrow[jc + 0] = (float)c0 / 15.0f;
    rrow[jc + 1] = (float)c1 / 15.0f;
    rrow[jc + 2] = (float)c2 / 15.0f;
    rrow[jc + 3] = (float)c3 / 15.0f;
    __syncthreads();
    if (tid < D_OUT) {
        float a = bout[tid];
        const float* wrow = Wout + (size_t)tid * H_SZ;
        for (int j = 0; j < H_SZ; ++j) a = fmaf(rrow[j], wrow[j], a);
        out[(size_t)b * D_OUT + tid] = a;
    }
}

// ---------------------------------------------------------------- launch
extern "C" void kernel_launch(void* const* d_in, const int* in_sizes, int n_in,
                              void* d_out, int out_size, void* d_ws, size_t ws_size,
                              hipStream_t stream) {
    const float* x    = (const float*)d_in[0];
    const float* W1   = (const float*)d_in[1];
    const float* b1   = (const float*)d_in[2];
    const float* W2   = (const float*)d_in[3];
    const float* b2   = (const float*)d_in[4];
    const float* Wout = (const float*)d_in[5];
    const float* bout = (const float*)d_in[6];
    float* out = (float*)d_out;

    char* ws = (char*)d_ws;
    unsigned short* W2cb  = (unsigned short*)(ws);              // 2 MB + 2 KB pad row
    int*            flags = (int*)(ws + (4 << 20));             // 32 KB
    unsigned char*  kbuf  = (unsigned char*)(ws + (8 << 20));   // 8 MB intervals

    k0_transpose<<<dim3(H_SZ / 32, H_SZ / 32), dim3(32, 8), 0, stream>>>(W2, W2cb, flags);
    k1_mfma<<<dim3(B_SZ / 128, H_SZ / 128), 256, 0, stream>>>(x, W1, b1, kbuf);
    k2_cert<<<B_SZ, 256, 0, stream>>>(kbuf, W2cb, b2, bout, flags, out);
    k3_rare<<<B_SZ, 256, 0, stream>>>(kbuf, W2cb, b2, Wout, bout, flags, out);
}

// Round 18
// 53.166 us; speedup vs baseline: 2.5476x; 1.2869x over previous
//
#include <hip/hip_runtime.h>
#include <hip/hip_bf16.h>

// SpikingPolicyNet: B=8192, D_in=256, H=1024, D_out=64, T=15, TAU=20, V_TH=1
//
// Pipeline (R18: no per-row W2 gather in the common path):
//  memset: cert[8192], mx[1024], mxb2 <- 0  (ws not re-poisoned between calls)
//  K0 : W2 -> W2cb (bf16 W2^T + zero sentinel row, for the rare path only);
//       column maxima mx[j] = max_i relu(W2[i][j]) (atomicMax on uint bits);
//       mxb2 = max_i relu(b2_i).
//  K1 : bf16-MFMA x@W1.T; epilogue folds b1, computes the closed-form spike
//       interval k = ceil(log2(1-1/I)/log2(0.95)) (spikes at t=k,2k,...; I1
//       time-invariant), writes byte-plane kb[b][j], and for spikers adds
//       CTAB[k]*mx[j] into cert[b] (one float atomic per spiker, ~3%).
//  K2 : per-row: certv = cert[b] + 0.5367*mxb2. Soundness:
//         v2_t(no-reset) = 0.05*sum_s 0.95^(t-s) I2_s >= v2_t(with resets);
//         I2_s <= relu(b2_i) + sum_j relu(w_ij)[k_j | s]
//         => max_i,t v2 <= 0.5367*max relu(b2) + sum_j coef(k_j)*mx[j]
//       coef(k) = 0.05*max_t sum_{m:mk<=t<=15} 0.95^(t-mk) (=0.05 for k>=8);
//       CTAB[k]=coef(k-1) absorbs +-1 k-flips. certv <= 0.98 (typ ~0.2,
//       ~25-sigma margin) proves zero s2 spikes -> out = bout (bit-exact;
//       absmax==0 R1-R17 incl full-fp32 R1). Cert-failing rows (expected 0)
//       run R16/R17's proven exact 8-bucket G-register recurrence inline.

#define B_SZ   8192
#define D_IN   256
#define H_SZ   1024
#define D_OUT  64
#define T_STEPS 15
#define CERT_THR 0.98f

typedef __attribute__((ext_vector_type(8))) short short8;
typedef __attribute__((ext_vector_type(4))) float f32x4;

__device__ __constant__ float CTAB[16] = {   // CTAB[k] = coef(k-1), k-flip robust
    0.05f,     0.53670f, 0.53670f, 0.26271f, 0.18815f, 0.12390f, 0.11863f,
    0.086755f, 0.084882f, 0.05f,   0.05f,    0.05f,    0.05f,    0.05f,
    0.05f,     0.05f};

static __device__ __forceinline__ unsigned int pk_bf16(float lo, float hi) {
    return (__builtin_bit_cast(unsigned int, hi) & 0xffff0000u) |
           (__builtin_bit_cast(unsigned int, lo) >> 16);
}
static __device__ __forceinline__ f32x4 unp4(uint2 w) {
    f32x4 r;
    r.x = __builtin_bit_cast(float, w.x << 16);
    r.y = __builtin_bit_cast(float, w.x & 0xffff0000u);
    r.z = __builtin_bit_cast(float, w.y << 16);
    r.w = __builtin_bit_cast(float, w.y & 0xffff0000u);
    return r;
}

// ---------------------------------------------------------------- K0: transpose + colmax + b2max
__global__ __launch_bounds__(256) void k0_prep(const float* __restrict__ W2,
                                               const float* __restrict__ b2,
                                               unsigned short* __restrict__ W2cb,
                                               unsigned int* __restrict__ mxbits,
                                               unsigned int* __restrict__ mxb2) {
    __shared__ float tile[32][33];
    const int bx = blockIdx.x * 32;
    const int by = blockIdx.y * 32;
    const int tx = threadIdx.x;
    const int ty = threadIdx.y;
    #pragma unroll
    for (int i = ty; i < 32; i += 8)
        tile[i][tx] = W2[(size_t)(by + i) * H_SZ + bx + tx];
    __syncthreads();
    #pragma unroll
    for (int i = ty; i < 32; i += 8)
        W2cb[(size_t)(bx + i) * H_SZ + by + tx] =
            (unsigned short)(__builtin_bit_cast(unsigned int, tile[tx][i]) >> 16);
    if (ty == 0) {                                   // column max (col j = bx+tx)
        float m = 0.f;
        #pragma unroll
        for (int i = 0; i < 32; ++i) m = fmaxf(m, tile[i][tx]);
        atomicMax(&mxbits[bx + tx], __builtin_bit_cast(unsigned int, m));
    }
    if (blockIdx.x == 0 && blockIdx.y == 0) {        // zero sentinel row 1024
        const int t = ty * 32 + tx;
        #pragma unroll
        for (int i = 0; i < 4; ++i)
            W2cb[(size_t)H_SZ * H_SZ + i * 256 + t] = 0;
    }
    if (blockIdx.x == 0 && blockIdx.y == 1) {        // max relu(b2)
        const int t = ty * 32 + tx;
        float m = 0.f;
        #pragma unroll
        for (int i = 0; i < 4; ++i) m = fmaxf(m, b2[t + 256 * i]);
        atomicMax(mxb2, __builtin_bit_cast(unsigned int, m));
    }
}

// ---------------------------------------------------------------- K1: MFMA + kb + cert atomics
__global__ __launch_bounds__(256) void k1_mfma(const float* __restrict__ A,
                                               const float* __restrict__ Bw,
                                               const float* __restrict__ b1,
                                               const float* __restrict__ mx,
                                               unsigned char* __restrict__ kb,
                                               float* __restrict__ cert) {
    __shared__ unsigned int As4[2048];   // 128 rows x 32 bf16, 16B-chunk XOR swizzle
    __shared__ unsigned int Bs4[2048];
    const int tid  = threadIdx.x;
    const int m0   = blockIdx.x * 128;
    const int n0   = blockIdx.y * 128;
    const int lane = tid & 63;
    const int wid  = tid >> 6;
    const int wr   = wid >> 1, wc = wid & 1;

    const int row0 = tid >> 2;
    const int row1 = row0 + 64;
    const int q0   = tid & 3;

    f32x4 acc[4][4] = {};
    float4 s0[8], s1[8];

    auto LOAD = [&](float4* s, int kbk) {
        const float* pa0 = A  + (m0 + row0) * D_IN + kbk + q0 * 8;
        const float* pa1 = A  + (m0 + row1) * D_IN + kbk + q0 * 8;
        const float* pb0 = Bw + (n0 + row0) * D_IN + kbk + q0 * 8;
        const float* pb1 = Bw + (n0 + row1) * D_IN + kbk + q0 * 8;
        s[0] = *(const float4*)pa0; s[1] = *(const float4*)(pa0 + 4);
        s[2] = *(const float4*)pa1; s[3] = *(const float4*)(pa1 + 4);
        s[4] = *(const float4*)pb0; s[5] = *(const float4*)(pb0 + 4);
        s[6] = *(const float4*)pb1; s[7] = *(const float4*)(pb1 + 4);
    };
    auto WRITE = [&](const float4* s) {
        const int i0 = row0 * 16 + (q0 ^ ((row0 >> 1) & 3)) * 4;
        const int i1 = row1 * 16 + (q0 ^ ((row1 >> 1) & 3)) * 4;
        *(uint4*)&As4[i0] = make_uint4(pk_bf16(s[0].x, s[0].y), pk_bf16(s[0].z, s[0].w),
                                       pk_bf16(s[1].x, s[1].y), pk_bf16(s[1].z, s[1].w));
        *(uint4*)&As4[i1] = make_uint4(pk_bf16(s[2].x, s[2].y), pk_bf16(s[2].z, s[2].w),
                                       pk_bf16(s[3].x, s[3].y), pk_bf16(s[3].z, s[3].w));
        *(uint4*)&Bs4[i0] = make_uint4(pk_bf16(s[4].x, s[4].y), pk_bf16(s[4].z, s[4].w),
                                       pk_bf16(s[5].x, s[5].y), pk_bf16(s[5].z, s[5].w));
        *(uint4*)&Bs4[i1] = make_uint4(pk_bf16(s[6].x, s[6].y), pk_bf16(s[6].z, s[6].w),
                                       pk_bf16(s[7].x, s[7].y), pk_bf16(s[7].z, s[7].w));
    };
    auto COMPUTE = [&]() {
        short8 afr[4], bfr[4];
        const int q  = lane >> 4;
        const int lr = lane & 15;
        #pragma unroll
        for (int mf = 0; mf < 4; ++mf) {
            const int ra = wr * 64 + mf * 16 + lr;
            afr[mf] = *(const short8*)&As4[ra * 16 + (q ^ ((ra >> 1) & 3)) * 4];
            const int rb = wc * 64 + mf * 16 + lr;
            bfr[mf] = *(const short8*)&Bs4[rb * 16 + (q ^ ((rb >> 1) & 3)) * 4];
        }
        #pragma unroll
        for (int mf = 0; mf < 4; ++mf)
            #pragma unroll
            for (int nf = 0; nf < 4; ++nf)
                acc[mf][nf] = __builtin_amdgcn_mfma_f32_16x16x32_bf16(
                    afr[mf], bfr[nf], acc[mf][nf], 0, 0, 0);
    };

    LOAD(s0, 0);
    for (int kk = 0; kk < D_IN; kk += 64) {
        if (kk + 32 < D_IN) LOAD(s1, kk + 32);
        __syncthreads();
        WRITE(s0);
        __syncthreads();
        COMPUTE();
        if (kk + 64 < D_IN) LOAD(s0, kk + 64);
        __syncthreads();
        WRITE(s1);
        __syncthreads();
        COMPUTE();
    }

    // Epilogue: I = acc + b1[col]; k = ceil(log2(1-1/I)*-13.5134035), 0 = none.
    const int lr = lane & 15;
    const int qq = lane >> 4;
    float b1v[4];
    #pragma unroll
    for (int nf = 0; nf < 4; ++nf) b1v[nf] = b1[n0 + wc * 64 + nf * 16 + lr];

    #pragma unroll
    for (int mf = 0; mf < 4; ++mf) {
        const int rbase = m0 + wr * 64 + mf * 16 + qq * 4;
        #pragma unroll
        for (int nf = 0; nf < 4; ++nf) {
            const int c = n0 + wc * 64 + nf * 16 + lr;
            const float mxc = mx[c];
            #pragma unroll
            for (int r = 0; r < 4; ++r) {
                const float I = acc[mf][nf][r] + b1v[nf];
                int k = 0;
                if (I > 1.8632055f) {
                    const float l2 = __builtin_amdgcn_logf(1.0f - __builtin_amdgcn_rcpf(I));
                    int kc = (int)__builtin_ceilf(l2 * -13.5134035f);
                    k = kc < 1 ? 1 : (kc > 15 ? 15 : kc);
                    atomicAdd(&cert[rbase + r], CTAB[k] * mxc);
                }
                kb[(size_t)(rbase + r) * H_SZ + c] = (unsigned char)k;
            }
        }
    }
}

// ---------------------------------------------------------------- K2: cert check + bout (+ exact fallback)
#define BQ(IDX, GV)                                                           \
    { const uint2 eq = *(const uint2*)&ent[IDX];                              \
      const unsigned sa = (unsigned)__builtin_amdgcn_readfirstlane((int)eq.x);\
      const unsigned sb = (unsigned)__builtin_amdgcn_readfirstlane((int)eq.y);\
      const uint2 qa = *(const uint2*)(W2cb + ((size_t)(sa & 0xffffu) << 10) + jc); \
      const uint2 qb = *(const uint2*)(W2cb + ((size_t)(sa >> 16) << 10) + jc);     \
      const uint2 qc = *(const uint2*)(W2cb + ((size_t)(sb & 0xffffu) << 10) + jc); \
      const uint2 qd = *(const uint2*)(W2cb + ((size_t)(sb >> 16) << 10) + jc);     \
      GV += unp4(qa); GV += unp4(qb); GV += unp4(qc); GV += unp4(qd); }

#define BLOOP(GV, R)                                                          \
    for (int i = stt[R]; i < stt[(R) + 1]; i += 4) BQ(i, GV)

__host__ __device__ constexpr unsigned divmask(int t) {   // bit k set iff k | t
    unsigned m = 0;
    for (int k = 1; k <= 15; ++k) if (t % k == 0) m |= 1u << k;
    return m;
}

#define SMALLT(T)                                                             \
    { constexpr unsigned dm = divmask(T);                                     \
      for (int i = 0; i < nsm; ++i) {                                         \
          const int ee = __builtin_amdgcn_readfirstlane((int)ent[i]);         \
          if ((dm >> (ee >> 12)) & 1) {                                       \
              const uint2 w = *(const uint2*)(W2cb + ((size_t)(ee & 0xfffu) << 10) + jc); \
              i2 += unp4(w); } } }

#define STEP                                                                  \
    { v2 = v2 * 0.95f + i2 * 0.05f;                                           \
      if (v2.x > 1.0f) { v2.x = 0.f; ++c0; }                                  \
      if (v2.y > 1.0f) { v2.y = 0.f; ++c1; }                                  \
      if (v2.z > 1.0f) { v2.z = 0.f; ++c2; }                                  \
      if (v2.w > 1.0f) { v2.w = 0.f; ++c3; } }

__global__ __launch_bounds__(256) void k2_final(const unsigned char* __restrict__ kb,
                                                const unsigned short* __restrict__ W2cb,
                                                const float* __restrict__ b2,
                                                const float* __restrict__ Wout,
                                                const float* __restrict__ bout,
                                                const float* __restrict__ cert,
                                                const unsigned int* __restrict__ mxb2,
                                                float* __restrict__ out) {
    const int b   = blockIdx.x;
    const int tid = threadIdx.x;
    const int jc  = tid * 4;

    const float certv = cert[b] +
        0.536708f * __builtin_bit_cast(float, *mxb2);

    if (certv <= CERT_THR) {                 // ~always: proven spike-free
        if (tid < D_OUT) out[(size_t)b * D_OUT + tid] = bout[tid];
        return;
    }

    // ---- exact path (R16/R17-proven): 8-bucket G-register recurrence
    __shared__ int cnt[16];                  // [0] = small (k<=7), [8..15] = big
    __shared__ int curs[16];
    __shared__ int stb[9];
    __shared__ int tot;
    __shared__ __align__(8) unsigned short ent[1064];
    __shared__ float rrow[H_SZ];

    if (tid < 16) { cnt[tid] = 0; if (tid == 0) tot = 0; }
    const unsigned int kw = *(const unsigned int*)(kb + (size_t)b * H_SZ + jc);
    const f32x4 b2q = *(const f32x4*)&b2[jc];
    __syncthreads();

    if (kw) {
        #pragma unroll
        for (int u = 0; u < 4; ++u) {
            const unsigned int ku = (kw >> (8 * u)) & 0xffu;
            if (ku) atomicAdd(&cnt[(ku >= 8) ? (int)ku : 0], 1);
        }
    }
    __syncthreads();
    if (tid < 9) {
        int s = (cnt[0] + 3) & ~3;
        for (int r = 0; r < tid; ++r) s += (cnt[8 + r] + 3) & ~3;
        stb[tid] = s;
        if (tid < 8) curs[8 + tid] = s;
        if (tid == 0) curs[0] = 0;
    }
    __syncthreads();
    if (kw) {
        #pragma unroll
        for (int u = 0; u < 4; ++u) {
            const unsigned int ku = (kw >> (8 * u)) & 0xffu;
            if (ku) {
                if (ku >= 8) {
                    const int p = atomicAdd(&curs[ku], 1);
                    ent[p] = (unsigned short)(jc + u);
                } else {
                    const int p = atomicAdd(&curs[0], 1);
                    ent[p] = (unsigned short)((jc + u) | (ku << 12));
                }
            }
        }
    }
    if (tid < 8) {
        for (int p = stb[tid] + cnt[8 + tid]; p < stb[tid + 1]; ++p)
            ent[p] = (unsigned short)H_SZ;
    }
    __syncthreads();

    int stt[9];
    #pragma unroll
    for (int r = 0; r < 9; ++r) stt[r] = __builtin_amdgcn_readfirstlane(stb[r]);
    const int nsm = __builtin_amdgcn_readfirstlane(cnt[0]);

    f32x4 G8 = {0,0,0,0}, G9 = {0,0,0,0}, G10 = {0,0,0,0}, G11 = {0,0,0,0};
    f32x4 G12 = {0,0,0,0}, G13 = {0,0,0,0}, G14 = {0,0,0,0}, G15 = {0,0,0,0};
    BLOOP(G8, 0)  BLOOP(G9, 1)  BLOOP(G10, 2) BLOOP(G11, 3)
    BLOOP(G12, 4) BLOOP(G13, 5) BLOOP(G14, 6) BLOOP(G15, 7)

    f32x4 v2 = {0,0,0,0};
    int c0 = 0, c1 = 0, c2 = 0, c3 = 0;
    { f32x4 i2 = b2q;       SMALLT(1)  STEP }
    { f32x4 i2 = b2q;       SMALLT(2)  STEP }
    { f32x4 i2 = b2q;       SMALLT(3)  STEP }
    { f32x4 i2 = b2q;       SMALLT(4)  STEP }
    { f32x4 i2 = b2q;       SMALLT(5)  STEP }
    { f32x4 i2 = b2q;       SMALLT(6)  STEP }
    { f32x4 i2 = b2q;       SMALLT(7)  STEP }
    { f32x4 i2 = b2q + G8;  SMALLT(8)  STEP }
    { f32x4 i2 = b2q + G9;  SMALLT(9)  STEP }
    { f32x4 i2 = b2q + G10; SMALLT(10) STEP }
    { f32x4 i2 = b2q + G11; SMALLT(11) STEP }
    { f32x4 i2 = b2q + G12; SMALLT(12) STEP }
    { f32x4 i2 = b2q + G13; SMALLT(13) STEP }
    { f32x4 i2 = b2q + G14; SMALLT(14) STEP }
    { f32x4 i2 = b2q + G15; SMALLT(15) STEP }

    const int my = c0 + c1 + c2 + c3;
    if (my) atomicAdd(&tot, my);
    __syncthreads();

    if (tot == 0) {
        if (tid < D_OUT) out[(size_t)b * D_OUT + tid] = bout[tid];
        return;
    }

    rrow[jc + 0] = (float)c0 / 15.0f;
    rrow[jc + 1] = (float)c1 / 15.0f;
    rrow[jc + 2] = (float)c2 / 15.0f;
    rrow[jc + 3] = (float)c3 / 15.0f;
    __syncthreads();
    if (tid < D_OUT) {
        float a = bout[tid];
        const float* wrow = Wout + (size_t)tid * H_SZ;
        for (int j = 0; j < H_SZ; ++j) a = fmaf(rrow[j], wrow[j], a);
        out[(size_t)b * D_OUT + tid] = a;
    }
}

// ---------------------------------------------------------------- launch
extern "C" void kernel_launch(void* const* d_in, const int* in_sizes, int n_in,
                              void* d_out, int out_size, void* d_ws, size_t ws_size,
                              hipStream_t stream) {
    const float* x    = (const float*)d_in[0];
    const float* W1   = (const float*)d_in[1];
    const float* b1   = (const float*)d_in[2];
    const float* W2   = (const float*)d_in[3];
    const float* b2   = (const float*)d_in[4];
    const float* Wout = (const float*)d_in[5];
    const float* bout = (const float*)d_in[6];
    float* out = (float*)d_out;

    char* ws = (char*)d_ws;
    unsigned short* W2cb = (unsigned short*)(ws);                   // 2 MB + 2 KB pad
    float*          cert = (float*)(ws + (4 << 20));                // 32 KB
    float*          mx   = (float*)(ws + (4 << 20) + (32 << 10));   // 4 KB
    unsigned int*   mxb2 = (unsigned int*)(ws + (4 << 20) + (36 << 10)); // 4 B
    unsigned char*  kbuf = (unsigned char*)(ws + (8 << 20));        // 8 MB

    hipMemsetAsync(ws + (4 << 20), 0, (40 << 10), stream);          // cert+mx+mxb2
    k0_prep<<<dim3(H_SZ / 32, H_SZ / 32), dim3(32, 8), 0, stream>>>(
        W2, b2, W2cb, (unsigned int*)mx, mxb2);
    k1_mfma<<<dim3(B_SZ / 128, H_SZ / 128), 256, 0, stream>>>(x, W1, b1, mx, kbuf, cert);
    k2_final<<<B_SZ, 256, 0, stream>>>(kbuf, W2cb, b2, Wout, bout, cert, mxb2, out);
}